// Round 1
// baseline (2935.119 us; speedup 1.0000x reference)
//
#include <hip/hip_runtime.h>
#include <hip/hip_bf16.h>

// Problem constants: B=256, F=64, H=W=64, D=256, HC=32
// d_in: 0:x(256,256) 1:state(256,64,64,64) 2:index(256,2) 3:c1w 4:c1b 5:c2w 6:c2b
//       7:c3w 8:c3b 9:lin_w(131072,64) 10:lin_b 11:write_w(384,64) 12:write_b
// d_out: out(256,128) fp32 ++ new_state(256,64,64,64) fp32
// Scratch lives INSIDE d_out's new_state region until the copy kernel runs.

__device__ inline float ldval(const float* __restrict__ p) { return *p; }
__device__ inline float ldval(const __hip_bfloat16* __restrict__ p) { return __bfloat162float(*p); }

// ---------------------------------------------------------------------------
// 3x3 SAME conv + bias + relu, out bf16. Block: 256 thr, 32x32 spatial tile,
// each thread computes 4 pixels (y,x),(y,x+16),(y+1,x),(y+1,x+16) x 32 co.
// ---------------------------------------------------------------------------
template<int CIN, typename TIN>
__global__ __launch_bounds__(256)
void conv3x3_relu_k(const TIN* __restrict__ in,        // (256, CIN, 64, 64)
                    const float* __restrict__ wgt,     // (32, CIN, 3, 3)
                    const float* __restrict__ bias,    // (32)
                    __hip_bfloat16* __restrict__ out)  // (256, 32, 64, 64)
{
    constexpr int CIc = 8;
    __shared__ float s_in[CIc][34][35];   // +1 pad breaks pow2 strides
    __shared__ float s_w[CIc][32][9];

    const int b   = blockIdx.x;
    const int ty0 = (blockIdx.y >> 1) * 32;
    const int tx0 = (blockIdx.y & 1) * 32;
    const int t   = threadIdx.x;
    const int tx  = t & 15;          // pixel cols: tx, tx+16
    const int ty  = (t >> 4) * 2;    // pixel rows: ty, ty+1

    float acc[4][32];
    #pragma unroll
    for (int p = 0; p < 4; ++p)
        #pragma unroll
        for (int co = 0; co < 32; ++co) acc[p][co] = 0.f;

    for (int c0 = 0; c0 < CIN; c0 += CIc) {
        for (int idx = t; idx < CIc * 34 * 34; idx += 256) {
            int ci = idx / (34 * 34);
            int r  = idx - ci * (34 * 34);
            int y  = r / 34;
            int x  = r - y * 34;
            int gy = ty0 + y - 1;
            int gx = tx0 + x - 1;
            float v = 0.f;
            if (gy >= 0 && gy < 64 && gx >= 0 && gx < 64)
                v = ldval(&in[(((size_t)b * CIN + c0 + ci) * 64 + gy) * 64 + gx]);
            s_in[ci][y][x] = v;
        }
        for (int idx = t; idx < CIc * 32 * 9; idx += 256) {
            int ci = idx / (32 * 9);
            int r  = idx - ci * (32 * 9);
            int co = r / 9;
            int k  = r - co * 9;
            s_w[ci][co][k] = wgt[(co * CIN + c0 + ci) * 9 + k];
        }
        __syncthreads();

        for (int ci = 0; ci < CIc; ++ci) {
            #pragma unroll
            for (int ky = 0; ky < 3; ++ky) {
                #pragma unroll
                for (int kx = 0; kx < 3; ++kx) {
                    float i00 = s_in[ci][ty + ky][tx + kx];
                    float i01 = s_in[ci][ty + ky][tx + 16 + kx];
                    float i10 = s_in[ci][ty + 1 + ky][tx + kx];
                    float i11 = s_in[ci][ty + 1 + ky][tx + 16 + kx];
                    #pragma unroll
                    for (int co = 0; co < 32; ++co) {
                        float wv = s_w[ci][co][ky * 3 + kx];
                        acc[0][co] += i00 * wv;
                        acc[1][co] += i01 * wv;
                        acc[2][co] += i10 * wv;
                        acc[3][co] += i11 * wv;
                    }
                }
            }
        }
        __syncthreads();
    }

    const int y0 = ty0 + ty;
    const int x0 = tx0 + tx;
    #pragma unroll
    for (int co = 0; co < 32; ++co) {
        float bv = bias[co];
        size_t base = ((size_t)b * 32 + co) * 4096;
        out[base + (size_t)y0 * 64 + x0]            = __float2bfloat16(fmaxf(acc[0][co] + bv, 0.f));
        out[base + (size_t)y0 * 64 + x0 + 16]       = __float2bfloat16(fmaxf(acc[1][co] + bv, 0.f));
        out[base + (size_t)(y0 + 1) * 64 + x0]      = __float2bfloat16(fmaxf(acc[2][co] + bv, 0.f));
        out[base + (size_t)(y0 + 1) * 64 + x0 + 16] = __float2bfloat16(fmaxf(acc[3][co] + bv, 0.f));
    }
}

// ---------------------------------------------------------------------------
// Linear stage 1: split-K GEMM. M=256(b) N=64(f) K=131072. 256 blocks, each
// owns a K-chunk of 512 and produces a full 256x64 partial.
// Thread: 16 b x 4 f accumulators.
// ---------------------------------------------------------------------------
__global__ __launch_bounds__(256)
void lin_partial_k(const __hip_bfloat16* __restrict__ h3,  // (256, 131072)
                   const float* __restrict__ lw,           // (131072, 64)
                   float* __restrict__ partial)            // (256, 256*64)
{
    __shared__ float s_h[32][260];   // [k][b], stride 260: 16B-aligned rows, conflict-benign
    __shared__ float s_w[32][64];    // [k][f]
    const int t  = threadIdx.x;
    const int k0 = blockIdx.x * 512;
    const int f0 = (t & 15) * 4;
    const int b0 = (t >> 4) * 16;

    float acc[16][4];
    #pragma unroll
    for (int i = 0; i < 16; ++i)
        #pragma unroll
        for (int j = 0; j < 4; ++j) acc[i][j] = 0.f;

    for (int kk = 0; kk < 512; kk += 32) {
        #pragma unroll
        for (int i = 0; i < 8; ++i) {              // 2048 x (4 bf16) loads
            int id = i * 256 + t;
            int bb = id >> 3;
            int pc = id & 7;
            ushort4 hv = *(const ushort4*)(h3 + (size_t)bb * 131072 + k0 + kk + pc * 4);
            s_h[pc * 4 + 0][bb] = __uint_as_float((unsigned)hv.x << 16);
            s_h[pc * 4 + 1][bb] = __uint_as_float((unsigned)hv.y << 16);
            s_h[pc * 4 + 2][bb] = __uint_as_float((unsigned)hv.z << 16);
            s_h[pc * 4 + 3][bb] = __uint_as_float((unsigned)hv.w << 16);
        }
        #pragma unroll
        for (int i = 0; i < 2; ++i) {              // 512 float4 loads
            int id = i * 256 + t;
            int kr = id >> 4;
            int c4 = (id & 15) * 4;
            float4 wv = *(const float4*)&lw[(size_t)(k0 + kk + kr) * 64 + c4];
            *(float4*)&s_w[kr][c4] = wv;
        }
        __syncthreads();
        for (int k = 0; k < 32; ++k) {
            float4 wv = *(const float4*)&s_w[k][f0];
            #pragma unroll
            for (int ii = 0; ii < 4; ++ii) {
                float4 hv = *(const float4*)&s_h[k][b0 + ii * 4];
                float hvv[4] = {hv.x, hv.y, hv.z, hv.w};
                #pragma unroll
                for (int l = 0; l < 4; ++l) {
                    acc[ii * 4 + l][0] += hvv[l] * wv.x;
                    acc[ii * 4 + l][1] += hvv[l] * wv.y;
                    acc[ii * 4 + l][2] += hvv[l] * wv.z;
                    acc[ii * 4 + l][3] += hvv[l] * wv.w;
                }
            }
        }
        __syncthreads();
    }

    float* pp = partial + (size_t)blockIdx.x * 16384;
    #pragma unroll
    for (int i = 0; i < 16; ++i) {
        float4 v = make_float4(acc[i][0], acc[i][1], acc[i][2], acc[i][3]);
        *(float4*)&pp[(b0 + i) * 64 + f0] = v;
    }
}

// Stage 2: reduce 256 partials, + bias, relu, write r into out[b*128 + f].
__global__ __launch_bounds__(256)
void lin_reduce_k(const float* __restrict__ partial,
                  const float* __restrict__ lb,
                  float* __restrict__ out)
{
    int idx = blockIdx.x * 256 + threadIdx.x;   // 16384
    int b = idx >> 6, f = idx & 63;
    float s = lb[f];
    for (int c = 0; c < 256; ++c) s += partial[(size_t)c * 16384 + idx];
    out[(size_t)b * 128 + f] = fmaxf(s, 0.f);
}

// w = [x | r | m] @ write_w + write_b  -> out[b*128 + 64 + f]
__global__ __launch_bounds__(256)
void write_k(const float* __restrict__ x,
             const float* __restrict__ state,
             const int* __restrict__ index,
             const float* __restrict__ ww,
             const float* __restrict__ wb,
             float* __restrict__ out)
{
    int idx = blockIdx.x * 256 + threadIdx.x;   // 16384
    int b = idx >> 6, f = idx & 63;
    int i0 = index[b * 2 + 0];
    int i1 = index[b * 2 + 1];
    float s = wb[f];
    for (int k = 0; k < 256; ++k) s += x[(size_t)b * 256 + k] * ww[k * 64 + f];
    for (int k = 0; k < 64; ++k)  s += out[(size_t)b * 128 + k] * ww[(256 + k) * 64 + f];
    const float* mp = state + (size_t)b * 262144 + (size_t)i0 * 64 + i1;
    for (int k = 0; k < 64; ++k)  s += mp[(size_t)k * 4096] * ww[(320 + k) * 64 + f];
    out[(size_t)b * 128 + 64 + f] = s;
}

__global__ __launch_bounds__(256)
void copy_state_k(const float4* __restrict__ src, float4* __restrict__ dst, int n4)
{
    int stride = gridDim.x * blockDim.x;
    for (int i = blockIdx.x * blockDim.x + threadIdx.x; i < n4; i += stride)
        dst[i] = src[i];
}

__global__ __launch_bounds__(256)
void scatter_k(const int* __restrict__ index,
               const float* __restrict__ out_ro,
               float* __restrict__ ns)
{
    int idx = blockIdx.x * 256 + threadIdx.x;   // 16384
    int b = idx >> 6, f = idx & 63;
    int i0 = index[b * 2 + 0];
    int i1 = index[b * 2 + 1];
    ns[(((size_t)b * 64 + f) * 64 + i0) * 64 + i1] = out_ro[(size_t)b * 128 + 64 + f];
}

extern "C" void kernel_launch(void* const* d_in, const int* in_sizes, int n_in,
                              void* d_out, int out_size, void* d_ws, size_t ws_size,
                              hipStream_t stream)
{
    (void)in_sizes; (void)n_in; (void)out_size; (void)d_ws; (void)ws_size;
    const float* x     = (const float*)d_in[0];
    const float* state = (const float*)d_in[1];
    const int*   idx   = (const int*)d_in[2];
    const float* c1w   = (const float*)d_in[3];
    const float* c1b   = (const float*)d_in[4];
    const float* c2w   = (const float*)d_in[5];
    const float* c2b   = (const float*)d_in[6];
    const float* c3w   = (const float*)d_in[7];
    const float* c3b   = (const float*)d_in[8];
    const float* lw    = (const float*)d_in[9];
    const float* lb    = (const float*)d_in[10];
    const float* ww    = (const float*)d_in[11];
    const float* wb    = (const float*)d_in[12];

    float* out = (float*)d_out;
    float* ns  = out + 32768;                       // new_state region, used as scratch first
    __hip_bfloat16* h1 = (__hip_bfloat16*)ns;       // 33.5M bf16 = 64 MB
    __hip_bfloat16* h2 = (__hip_bfloat16*)(ns + 16777216);
    __hip_bfloat16* h3 = h1;                        // conv3 reads h2, reuses h1 space
    float* partial = ns + 33554432;                 // 16 MB

    conv3x3_relu_k<64, float>         <<<dim3(256, 4), 256, 0, stream>>>(state, c1w, c1b, h1);
    conv3x3_relu_k<32, __hip_bfloat16><<<dim3(256, 4), 256, 0, stream>>>(h1, c2w, c2b, h2);
    conv3x3_relu_k<32, __hip_bfloat16><<<dim3(256, 4), 256, 0, stream>>>(h2, c3w, c3b, h3);
    lin_partial_k<<<256, 256, 0, stream>>>(h3, lw, partial);
    lin_reduce_k <<<64, 256, 0, stream>>>(partial, lb, out);
    write_k      <<<64, 256, 0, stream>>>(x, state, idx, ww, wb, out);
    copy_state_k <<<8192, 256, 0, stream>>>((const float4*)state, (float4*)ns, 16777216);
    scatter_k    <<<64, 256, 0, stream>>>(idx, out, ns);
}